// Round 17
// baseline (116.712 us; speedup 1.0000x reference)
//
#include <hip/hip_runtime.h>
#include <math.h>

constexpr int DIM   = 128;
constexpr int KC    = 1024;
constexpr int NROWS = 65536;                 // 16384*512/128
constexpr int XEL   = NROWS * DIM;           // 8388608

// output layout (floats)
constexpr int OUT_Z     = 0;
constexpr int OUT_DIFF  = XEL;               // 8388608
constexpr int OUT_CODES = XEL + 1;           // 8388609
constexpr int OUT_PPL   = XEL + 1 + NROWS;   // 8454145

// ws layout (4-byte units)
constexpr int WS_IDX  = 0;                   // int[NROWS]
constexpr int WS_FLAG = NROWS;               // int[NROWS]
constexpr int WS_CNT  = 2 * NROWS;           // int   (zeroed by k_prep)
constexpr int WS_DONE = WS_CNT + 1;          // u32   (zeroed by k_prep)
constexpr int WS_DCOR = WS_CNT + 2;          // double (2 words, 8B-aligned, zeroed)
constexpr int WS_HIST = WS_DCOR + 2;         // u32[KC] (zeroed by k_prep)
constexpr int WS_HN   = WS_HIST + KC;        // float[KC]
constexpr int WS_PART = WS_HN + KC;          // float[2048] diff partials
constexpr int WS_HN64 = WS_PART + 2048;      // double[KC]
constexpr int WS_EF   = WS_HN64 + 2 * KC;    // _Float16[KC*DIM] = 65536 words
constexpr int WS_ET   = WS_EF + (KC * DIM / 2); // float[DIM*KC] = 131072 words

constexpr int NB_RECHECK = 1024;

constexpr float GAP_THR = 0.06f;

typedef _Float16 f16x8 __attribute__((ext_vector_type(8)));
typedef _Float16 f16x4 __attribute__((ext_vector_type(4)));
typedef float f32x4 __attribute__((ext_vector_type(4)));

// ---- emb -> f16 + transposed fp32 + fp64 half-norms; zero counters/hist ----
__global__ __launch_bounds__(256) void k_prep(
        const float* __restrict__ emb, _Float16* __restrict__ ef,
        float* __restrict__ embT, float* __restrict__ hn,
        double* __restrict__ hn64, unsigned* __restrict__ zbase) {
    __shared__ float ldsT[DIM][9];
    const int tid = threadIdx.x;
    if (blockIdx.x == 0)
        for (int i = tid; i < 4 + KC; i += 256) zbase[i] = 0u;  // CNT,DONE,DCOR,HIST
    const int cc   = tid >> 5;
    const int code = blockIdx.x * 8 + cc;
    const int jq   = tid & 31;
    float4 v = *(const float4*)(emb + (size_t)code * DIM + jq * 4);
    f16x4 h = { (_Float16)v.x, (_Float16)v.y, (_Float16)v.z, (_Float16)v.w };
    *(f16x4*)(ef + (size_t)code * DIM + jq * 4) = h;
    ldsT[jq * 4 + 0][cc] = v.x;
    ldsT[jq * 4 + 1][cc] = v.y;
    ldsT[jq * 4 + 2][cc] = v.z;
    ldsT[jq * 4 + 3][cc] = v.w;
    double s = (double)v.x * v.x + (double)v.y * v.y
             + (double)v.z * v.z + (double)v.w * v.w;
    #pragma unroll
    for (int m = 1; m < 32; m <<= 1) s += __shfl_xor(s, m);
    if (jq == 0) {
        hn[code]   = (float)(0.5 * s);
        hn64[code] = 0.5 * s;
    }
    __syncthreads();
    #pragma unroll
    for (int i = 0; i < 4; ++i) {
        int idx = i * 256 + tid;
        int j = idx >> 3, c = idx & 7;
        embT[(size_t)j * KC + blockIdx.x * 8 + c] = ldsT[j][c];
    }
}

// ---- main: tribuf argmin core + fused z/codes/diff epilogue + LDS hist ----
__global__ __launch_bounds__(256, 2) void k_argmin(
        const float* __restrict__ x, const _Float16* __restrict__ ef,
        const float* __restrict__ emb, const float* __restrict__ hn,
        int* __restrict__ idx_out, int* __restrict__ flag_cnt,
        int* __restrict__ flagged, float* __restrict__ out,
        float* __restrict__ part, unsigned* __restrict__ ghist) {
    __shared__ _Float16 bt[3][8192];          // 3 x 16KB rotating buffers
    __shared__ float hn_lds[KC];
    __shared__ unsigned hist_l[KC];
    __shared__ int idx_l[128];
    const int tid = threadIdx.x;
    const int l = tid & 63, w = tid >> 6;     // 4 waves
    const int lr = l & 15, lg = l >> 4;
    const int r0 = blockIdx.x * 128 + w * 32; // 32 rows per wave

    #pragma unroll
    for (int i = 0; i < 4; ++i) {
        hn_lds[i * 256 + tid] = hn[i * 256 + tid];
        hist_l[i * 256 + tid] = 0u;
    }

    // A fragments: 32 rows as f16 (2 row-groups x 4 k-tiles)
    f16x8 a[2][4];
    #pragma unroll
    for (int i = 0; i < 2; ++i) {
        const float* xr = x + (size_t)(r0 + i * 16 + lr) * DIM + lg * 8;
        #pragma unroll
        for (int kt = 0; kt < 4; ++kt) {
            float4 v0 = *(const float4*)(xr + kt * 32);
            float4 v1 = *(const float4*)(xr + kt * 32 + 4);
            f16x8 av = { (_Float16)v0.x, (_Float16)v0.y, (_Float16)v0.z, (_Float16)v0.w,
                         (_Float16)v1.x, (_Float16)v1.y, (_Float16)v1.z, (_Float16)v1.w };
            a[i][kt] = av;
        }
    }

    const _Float16* gsrc[4];
    #pragma unroll
    for (int i = 0; i < 4; ++i)
        gsrc[i] = ef + (size_t)(w * 16 + lr) * DIM + i * 32 + lg * 8;

    #define ISSUE_TILE(t, buf)                                                   \
        {                                                                        \
            _Pragma("unroll")                                                    \
            for (int i_ = 0; i_ < 4; ++i_) {                                     \
                const _Float16* g_ = gsrc[i_] + (size_t)(t) * 64 * DIM;          \
                __builtin_amdgcn_global_load_lds(                                \
                    (const __attribute__((address_space(1))) unsigned*)g_,       \
                    (__attribute__((address_space(3))) unsigned*)                \
                        &bt[buf][(w * 4 + i_) * 512],                            \
                    16, 0, 0);                                                   \
            }                                                                    \
        }

    ISSUE_TILE(0, 0)
    ISSUE_TILE(1, 1)
    asm volatile("s_waitcnt vmcnt(4)" ::: "memory");
    __syncthreads();

    float m1[2][4], m2[2][4]; int bi[2][4];
    #pragma unroll
    for (int i = 0; i < 2; ++i)
        #pragma unroll
        for (int rg = 0; rg < 4; ++rg) { m1[i][rg] = -3e38f; m2[i][rg] = -3e38f; bi[i][rg] = 0; }

    constexpr int NT = KC / 64;               // 16 tiles
    for (int t = 0; t < NT; ++t) {
        const int buf = t % 3;
        if (t + 2 < NT) ISSUE_TILE(t + 2, (t + 2) % 3)
        float hnv[4];
        #pragma unroll
        for (int c = 0; c < 4; ++c) hnv[c] = hn_lds[t * 64 + c * 16 + lr];
        f32x4 acc[2][4] = {};
        __builtin_amdgcn_s_setprio(1);
        #pragma unroll
        for (int kt = 0; kt < 4; ++kt) {
            f16x8 b[4];
            #pragma unroll
            for (int c = 0; c < 4; ++c)
                b[c] = *(const f16x8*)(&bt[buf][(c * 4 + kt) * 512 + l * 8]);
            #pragma unroll
            for (int i = 0; i < 2; ++i)
                #pragma unroll
                for (int c = 0; c < 4; ++c)
                    acc[i][c] = __builtin_amdgcn_mfma_f32_16x16x32_f16(a[i][kt], b[c], acc[i][c], 0, 0, 0);
        }
        __builtin_amdgcn_s_setprio(0);
        #pragma unroll
        for (int i = 0; i < 2; ++i)
            #pragma unroll
            for (int c = 0; c < 4; ++c) {
                const int cc = t * 64 + c * 16 + lr;
                #pragma unroll
                for (int rg = 0; rg < 4; ++rg) {
                    float v = acc[i][c][rg] - hnv[c];
                    bool g = v > m1[i][rg];
                    m2[i][rg] = fmaxf(fminf(v, m1[i][rg]), m2[i][rg]);
                    m1[i][rg] = fmaxf(m1[i][rg], v);
                    bi[i][rg] = g ? cc : bi[i][rg];
                }
            }
        if (t + 2 < NT) asm volatile("s_waitcnt vmcnt(4)" ::: "memory");
        else            asm volatile("s_waitcnt vmcnt(0)" ::: "memory");
        __syncthreads();
    }
    #undef ISSUE_TILE

    // merge top-2 across the 16 lanes sharing each row
    #pragma unroll
    for (int i = 0; i < 2; ++i)
        #pragma unroll
        for (int rg = 0; rg < 4; ++rg) {
            float a1 = m1[i][rg], a2 = m2[i][rg]; int ai = bi[i][rg];
            #pragma unroll
            for (int mask = 1; mask < 16; mask <<= 1) {
                float o1 = __shfl_xor(a1, mask);
                float o2 = __shfl_xor(a2, mask);
                int   oi = __shfl_xor(ai, mask);
                float nm2 = fmaxf(fmaxf(a2, o2), fminf(a1, o1));
                if (o1 > a1 || (o1 == a1 && oi < ai)) { a1 = o1; ai = oi; }
                a2 = nm2;
            }
            if (lr == 0) {
                int rl = w * 32 + i * 16 + lg * 4 + rg;
                int row = blockIdx.x * 128 + rl;
                idx_out[row] = ai;
                idx_l[rl] = ai;
                if (a1 - a2 < GAP_THR) {      // near-tie: exact recheck later
                    int p = atomicAdd(flag_cnt, 1);
                    flagged[p] = row;
                }
            }
        }
    __syncthreads();                          // idx_l visible to all

    // per-block LDS histogram of the 128 assignments
    if (tid < 128) atomicAdd(&hist_l[idx_l[tid]], 1u);

    // ---- fused epilogue: z, codes, diff partials (half-wave per row) ----
    const int c = tid & 31;                   // float4 column 0..31
    float d = 0.f;
    #pragma unroll
    for (int it = 0; it < 16; ++it) {
        const int rl = it * 8 + (tid >> 5);   // 8 rows per iteration
        const int row = blockIdx.x * 128 + rl;
        const int k = idx_l[rl];
        float4 xv = *(const float4*)(x + (size_t)row * DIM + c * 4);
        float4 qv = *(const float4*)(emb + (size_t)k * DIM + c * 4);
        float dx = qv.x - xv.x, dy = qv.y - xv.y, dz = qv.z - xv.z, dw = qv.w - xv.w;
        float4 z;
        z.x = xv.x + dx; z.y = xv.y + dy; z.z = xv.z + dz; z.w = xv.w + dw;
        *(float4*)(out + OUT_Z + (size_t)row * DIM + c * 4) = z;
        d += dx*dx + dy*dy + dz*dz + dw*dw;
        if (c == 0) out[OUT_CODES + row] = (float)k;
    }
    #pragma unroll
    for (int off = 32; off; off >>= 1) d += __shfl_down(d, off);
    if (l == 0) part[blockIdx.x * 4 + w] = d;

    __syncthreads();                          // all LDS-hist adds done
    #pragma unroll
    for (int i = 0; i < 4; ++i) {
        unsigned hc = hist_l[i * 256 + tid];
        if (hc) atomicAdd(&ghist[i * 256 + tid], hc);
    }
}

// ---- exact fp64 recheck + patch z/codes/diff/hist; last block finalizes ----
__global__ __launch_bounds__(256) void k_recheck(
        const float* __restrict__ x, const float* __restrict__ embT,
        const float* __restrict__ emb, const double* __restrict__ hn64,
        int* __restrict__ idx_out, const int* __restrict__ flag_cnt,
        const int* __restrict__ flagged, float* __restrict__ out,
        double* __restrict__ dcorr, unsigned* __restrict__ ghist,
        const float* __restrict__ part, unsigned* __restrict__ done) {
    __shared__ double xd[DIM];
    __shared__ double wv[4];
    __shared__ int    wk[4];
    __shared__ int    old_sh, fk_sh;
    __shared__ double dsum[128];
    __shared__ double sh[256];
    __shared__ unsigned rank_sh;
    const int tid = threadIdx.x;
    const int cnt = flag_cnt[0];
    for (int f = blockIdx.x; f < cnt; f += gridDim.x) {
        const int row = flagged[f];
        __syncthreads();                       // reuse guard
        if (tid < DIM) xd[tid] = (double)x[(size_t)row * DIM + tid];
        if (tid == 0) old_sh = idx_out[row];
        __syncthreads();
        const float* tp = embT + tid;
        double s0 = 0.0, s1 = 0.0, s2 = 0.0, s3 = 0.0;
        #pragma unroll 4
        for (int j = 0; j < DIM; ++j) {
            const float* rp = tp + (size_t)j * KC;
            double xv = xd[j];
            s0 = fma((double)rp[0],   xv, s0);
            s1 = fma((double)rp[256], xv, s1);
            s2 = fma((double)rp[512], xv, s2);
            s3 = fma((double)rp[768], xv, s3);
        }
        double bv = s0 - hn64[tid];       int bk = tid;
        double v1 = s1 - hn64[tid + 256];
        if (v1 > bv) { bv = v1; bk = tid + 256; }
        double v2 = s2 - hn64[tid + 512];
        if (v2 > bv) { bv = v2; bk = tid + 512; }
        double v3 = s3 - hn64[tid + 768];
        if (v3 > bv) { bv = v3; bk = tid + 768; }
        #pragma unroll
        for (int m = 1; m < 64; m <<= 1) {
            double ov = __shfl_xor(bv, m);
            int    ok = __shfl_xor(bk, m);
            if (ov > bv || (ov == bv && ok < bk)) { bv = ov; bk = ok; }
        }
        const int w = tid >> 6;
        if ((tid & 63) == 0) { wv[w] = bv; wk[w] = bk; }
        __syncthreads();
        if (tid == 0) {
            double fv = wv[0]; int fk = wk[0];
            #pragma unroll
            for (int i = 1; i < 4; ++i)
                if (wv[i] > fv || (wv[i] == fv && wk[i] < fk)) { fv = wv[i]; fk = wk[i]; }
            fk_sh = fk;
        }
        __syncthreads();
        const int fk = fk_sh, old = old_sh;
        if (fk != old) {                      // patch z, codes, diff, hist
            if (tid < DIM) {
                float xs = (float)xd[tid];
                float en = emb[(size_t)fk  * DIM + tid];
                float eo = emb[(size_t)old * DIM + tid];
                float dn = en - xs, dold = eo - xs;
                out[OUT_Z + (size_t)row * DIM + tid] = xs + dn;
                dsum[tid] = (double)dn * dn - (double)dold * dold;
            }
            __syncthreads();
            if (tid < 64) dsum[tid] += dsum[tid + 64];
            __syncthreads();
            if (tid < 64) {
                double v = dsum[tid];
                #pragma unroll
                for (int m = 32; m; m >>= 1) v += __shfl_down(v, m);
                if (tid == 0) {
                    atomicAdd(dcorr, v);
                    atomicAdd(&ghist[fk], 1u);
                    atomicAdd(&ghist[old], 0xFFFFFFFFu);   // -1
                    out[OUT_CODES + row] = (float)fk;
                    idx_out[row] = fk;
                }
            }
        }
    }
    __syncthreads();
    if (tid == 0) { __threadfence(); rank_sh = atomicAdd(done, 1u); }
    __syncthreads();
    if (rank_sh != NB_RECHECK - 1) return;

    // ---- last block: diff mean + perplexity ----
    double s = 0.0;
    #pragma unroll
    for (int it = 0; it < 2048 / 256; ++it) s += (double)part[it * 256 + tid];
    sh[tid] = s;
    __syncthreads();
    for (int st = 128; st; st >>= 1) {
        if (tid < st) sh[tid] += sh[tid + st];
        __syncthreads();
    }
    double diff = (sh[0] + atomicAdd(dcorr, 0.0)) * (1.0 / (double)XEL);
    double lp = 0.0;
    #pragma unroll
    for (int i = 0; i < KC / 256; ++i) {
        unsigned c = atomicAdd(&ghist[i * 256 + tid], 0u);   // coherent read
        double p = (double)c * (1.0 / (double)NROWS);
        lp += p * log(p + 1e-5);
    }
    __syncthreads();
    sh[tid] = lp;
    __syncthreads();
    for (int st = 128; st; st >>= 1) {
        if (tid < st) sh[tid] += sh[tid + st];
        __syncthreads();
    }
    if (tid == 0) {
        out[OUT_DIFF] = (float)diff;
        out[OUT_PPL]  = (float)(-sh[0]);
    }
}

extern "C" void kernel_launch(void* const* d_in, const int* in_sizes, int n_in,
                              void* d_out, int out_size, void* d_ws, size_t ws_size,
                              hipStream_t stream) {
    const float* x   = (const float*)d_in[0];
    const float* emb = (const float*)d_in[1];
    float* out = (float*)d_out;
    int*   wi  = (int*)d_ws;
    float* wf  = (float*)d_ws;
    unsigned* wu = (unsigned*)d_ws;
    double* hn64 = (double*)((float*)d_ws + WS_HN64);
    double* dcorr = (double*)((float*)d_ws + WS_DCOR);
    _Float16* ef = (_Float16*)((float*)d_ws + WS_EF);
    float* embT  = (float*)d_ws + WS_ET;

    k_prep<<<KC / 8, 256, 0, stream>>>(emb, ef, embT, wf + WS_HN, hn64, wu + WS_CNT);
    k_argmin<<<NROWS / 128, 256, 0, stream>>>(x, ef, emb, wf + WS_HN,
                                              wi + WS_IDX, wi + WS_CNT, wi + WS_FLAG,
                                              out, wf + WS_PART, wu + WS_HIST);
    k_recheck<<<NB_RECHECK, 256, 0, stream>>>(x, embT, emb, hn64, wi + WS_IDX,
                                              wi + WS_CNT, wi + WS_FLAG, out, dcorr,
                                              wu + WS_HIST, wf + WS_PART,
                                              wu + WS_DONE);
}

// Round 18
// 95.410 us; speedup vs baseline: 1.2233x; 1.2233x over previous
//
#include <hip/hip_runtime.h>
#include <math.h>

constexpr int DIM   = 128;
constexpr int KC    = 1024;
constexpr int NROWS = 65536;                 // 16384*512/128
constexpr int XEL   = NROWS * DIM;           // 8388608

// output layout (floats)
constexpr int OUT_Z     = 0;
constexpr int OUT_DIFF  = XEL;               // 8388608
constexpr int OUT_CODES = XEL + 1;           // 8388609
constexpr int OUT_PPL   = XEL + 1 + NROWS;   // 8454145

// ws layout (4-byte units)
constexpr int WS_IDX  = 0;                   // int[NROWS]
constexpr int WS_FLAG = NROWS;               // int[NROWS]
constexpr int WS_CNT  = 2 * NROWS;           // int   (zeroed by k_prep)
constexpr int WS_DONE = WS_CNT + 1;          // u32   (zeroed by k_prep)
constexpr int WS_DCOR = WS_CNT + 2;          // double (2 words, 8B-aligned, zeroed)
constexpr int WS_HIST = WS_DCOR + 2;         // u32[KC] (zeroed by k_prep)
constexpr int WS_HN   = WS_HIST + KC;        // float[KC]
constexpr int WS_PART = WS_HN + KC;          // float[2048] diff partials
constexpr int WS_HN64 = WS_PART + 2048;      // double[KC]
constexpr int WS_EF   = WS_HN64 + 2 * KC;    // _Float16[KC*DIM] = 65536 words
constexpr int WS_ET   = WS_EF + (KC * DIM / 2); // float[DIM*KC] = 131072 words

constexpr float GAP_THR = 0.06f;

typedef _Float16 f16x8 __attribute__((ext_vector_type(8)));
typedef _Float16 f16x4 __attribute__((ext_vector_type(4)));
typedef float f32x4 __attribute__((ext_vector_type(4)));

// ---- emb -> f16 + transposed fp32 + fp64 half-norms; zero counters/hist ----
__global__ __launch_bounds__(256) void k_prep(
        const float* __restrict__ emb, _Float16* __restrict__ ef,
        float* __restrict__ embT, float* __restrict__ hn,
        double* __restrict__ hn64, unsigned* __restrict__ zbase) {
    __shared__ float ldsT[DIM][9];
    const int tid = threadIdx.x;
    if (blockIdx.x == 0)
        for (int i = tid; i < 4 + KC; i += 256) zbase[i] = 0u;  // CNT,DONE,DCOR,HIST
    const int cc   = tid >> 5;
    const int code = blockIdx.x * 8 + cc;
    const int jq   = tid & 31;
    float4 v = *(const float4*)(emb + (size_t)code * DIM + jq * 4);
    f16x4 h = { (_Float16)v.x, (_Float16)v.y, (_Float16)v.z, (_Float16)v.w };
    *(f16x4*)(ef + (size_t)code * DIM + jq * 4) = h;
    ldsT[jq * 4 + 0][cc] = v.x;
    ldsT[jq * 4 + 1][cc] = v.y;
    ldsT[jq * 4 + 2][cc] = v.z;
    ldsT[jq * 4 + 3][cc] = v.w;
    double s = (double)v.x * v.x + (double)v.y * v.y
             + (double)v.z * v.z + (double)v.w * v.w;
    #pragma unroll
    for (int m = 1; m < 32; m <<= 1) s += __shfl_xor(s, m);
    if (jq == 0) {
        hn[code]   = (float)(0.5 * s);
        hn64[code] = 0.5 * s;
    }
    __syncthreads();
    #pragma unroll
    for (int i = 0; i < 4; ++i) {
        int idx = i * 256 + tid;
        int j = idx >> 3, c = idx & 7;
        embT[(size_t)j * KC + blockIdx.x * 8 + c] = ldsT[j][c];
    }
}

// ---- main: tribuf argmin core (STAGGERED tile order to kill L2 hot-spot)
// + fused z/codes/diff epilogue. ----
__global__ __launch_bounds__(256, 2) void k_argmin(
        const float* __restrict__ x, const _Float16* __restrict__ ef,
        const float* __restrict__ emb, const float* __restrict__ hn,
        int* __restrict__ idx_out, int* __restrict__ flag_cnt,
        int* __restrict__ flagged, float* __restrict__ out,
        float* __restrict__ part) {
    __shared__ _Float16 bt[3][8192];          // 3 x 16KB rotating buffers
    __shared__ float hn_lds[KC];
    __shared__ int idx_l[128];
    const int tid = threadIdx.x;
    const int l = tid & 63, w = tid >> 6;     // 4 waves
    const int lr = l & 15, lg = l >> 4;
    const int r0 = blockIdx.x * 128 + w * 32; // 32 rows per wave
    const int t0 = blockIdx.x & 15;           // staggered start tile

    #pragma unroll
    for (int i = 0; i < 4; ++i) hn_lds[i * 256 + tid] = hn[i * 256 + tid];

    // A fragments: 32 rows as f16 (2 row-groups x 4 k-tiles)
    f16x8 a[2][4];
    #pragma unroll
    for (int i = 0; i < 2; ++i) {
        const float* xr = x + (size_t)(r0 + i * 16 + lr) * DIM + lg * 8;
        #pragma unroll
        for (int kt = 0; kt < 4; ++kt) {
            float4 v0 = *(const float4*)(xr + kt * 32);
            float4 v1 = *(const float4*)(xr + kt * 32 + 4);
            f16x8 av = { (_Float16)v0.x, (_Float16)v0.y, (_Float16)v0.z, (_Float16)v0.w,
                         (_Float16)v1.x, (_Float16)v1.y, (_Float16)v1.z, (_Float16)v1.w };
            a[i][kt] = av;
        }
    }

    const _Float16* gsrc[4];
    #pragma unroll
    for (int i = 0; i < 4; ++i)
        gsrc[i] = ef + (size_t)(w * 16 + lr) * DIM + i * 32 + lg * 8;

    #define ISSUE_TILE(t, buf)                                                   \
        {                                                                        \
            _Pragma("unroll")                                                    \
            for (int i_ = 0; i_ < 4; ++i_) {                                     \
                const _Float16* g_ = gsrc[i_] + (size_t)(t) * 64 * DIM;          \
                __builtin_amdgcn_global_load_lds(                                \
                    (const __attribute__((address_space(1))) unsigned*)g_,       \
                    (__attribute__((address_space(3))) unsigned*)                \
                        &bt[buf][(w * 4 + i_) * 512],                            \
                    16, 0, 0);                                                   \
            }                                                                    \
        }

    ISSUE_TILE(t0, 0)
    ISSUE_TILE((t0 + 1) & 15, 1)
    asm volatile("s_waitcnt vmcnt(4)" ::: "memory");
    __syncthreads();

    float m1[2][4], m2[2][4]; int bi[2][4];
    #pragma unroll
    for (int i = 0; i < 2; ++i)
        #pragma unroll
        for (int rg = 0; rg < 4; ++rg) { m1[i][rg] = -3e38f; m2[i][rg] = -3e38f; bi[i][rg] = 0; }

    constexpr int NT = KC / 64;               // 16 tiles
    for (int t = 0; t < NT; ++t) {
        const int buf = t % 3;
        const int tt = (t0 + t) & 15;         // staggered tile index
        if (t + 2 < NT) ISSUE_TILE((t0 + t + 2) & 15, (t + 2) % 3)
        float hnv[4];
        #pragma unroll
        for (int c = 0; c < 4; ++c) hnv[c] = hn_lds[tt * 64 + c * 16 + lr];
        f32x4 acc[2][4] = {};
        __builtin_amdgcn_s_setprio(1);
        #pragma unroll
        for (int kt = 0; kt < 4; ++kt) {
            f16x8 b[4];
            #pragma unroll
            for (int c = 0; c < 4; ++c)
                b[c] = *(const f16x8*)(&bt[buf][(c * 4 + kt) * 512 + l * 8]);
            #pragma unroll
            for (int i = 0; i < 2; ++i)
                #pragma unroll
                for (int c = 0; c < 4; ++c)
                    acc[i][c] = __builtin_amdgcn_mfma_f32_16x16x32_f16(a[i][kt], b[c], acc[i][c], 0, 0, 0);
        }
        __builtin_amdgcn_s_setprio(0);
        #pragma unroll
        for (int i = 0; i < 2; ++i)
            #pragma unroll
            for (int c = 0; c < 4; ++c) {
                const int cc = tt * 64 + c * 16 + lr;
                #pragma unroll
                for (int rg = 0; rg < 4; ++rg) {
                    float v = acc[i][c][rg] - hnv[c];
                    bool g = v > m1[i][rg];
                    m2[i][rg] = fmaxf(fminf(v, m1[i][rg]), m2[i][rg]);
                    m1[i][rg] = fmaxf(m1[i][rg], v);
                    bi[i][rg] = g ? cc : bi[i][rg];
                }
            }
        if (t + 2 < NT) asm volatile("s_waitcnt vmcnt(4)" ::: "memory");
        else            asm volatile("s_waitcnt vmcnt(0)" ::: "memory");
        __syncthreads();
    }
    #undef ISSUE_TILE

    // merge top-2 across the 16 lanes sharing each row.
    // NOTE: staggered order can pick first-encountered (not smallest) index
    // on exact ties, but exact ties give gap==0 -> flagged -> fp64 recheck
    // restores first-min semantics.
    #pragma unroll
    for (int i = 0; i < 2; ++i)
        #pragma unroll
        for (int rg = 0; rg < 4; ++rg) {
            float a1 = m1[i][rg], a2 = m2[i][rg]; int ai = bi[i][rg];
            #pragma unroll
            for (int mask = 1; mask < 16; mask <<= 1) {
                float o1 = __shfl_xor(a1, mask);
                float o2 = __shfl_xor(a2, mask);
                int   oi = __shfl_xor(ai, mask);
                float nm2 = fmaxf(fmaxf(a2, o2), fminf(a1, o1));
                if (o1 > a1 || (o1 == a1 && oi < ai)) { a1 = o1; ai = oi; }
                a2 = nm2;
            }
            if (lr == 0) {
                int rl = w * 32 + i * 16 + lg * 4 + rg;
                int row = blockIdx.x * 128 + rl;
                idx_out[row] = ai;
                idx_l[rl] = ai;
                if (a1 - a2 < GAP_THR) {      // near-tie: exact recheck later
                    int p = atomicAdd(flag_cnt, 1);
                    flagged[p] = row;
                }
            }
        }
    __syncthreads();                          // idx_l visible to all

    // ---- fused epilogue: z, codes, diff partials (half-wave per row) ----
    const int c = tid & 31;                   // float4 column 0..31
    float d = 0.f;
    #pragma unroll
    for (int it = 0; it < 16; ++it) {
        const int rl = it * 8 + (tid >> 5);   // 8 rows per iteration
        const int row = blockIdx.x * 128 + rl;
        const int k = idx_l[rl];
        float4 xv = *(const float4*)(x + (size_t)row * DIM + c * 4);
        float4 qv = *(const float4*)(emb + (size_t)k * DIM + c * 4);
        float dx = qv.x - xv.x, dy = qv.y - xv.y, dz = qv.z - xv.z, dw = qv.w - xv.w;
        float4 z;
        z.x = xv.x + dx; z.y = xv.y + dy; z.z = xv.z + dz; z.w = xv.w + dw;
        *(float4*)(out + OUT_Z + (size_t)row * DIM + c * 4) = z;
        d += dx*dx + dy*dy + dz*dz + dw*dw;
        if (c == 0) out[OUT_CODES + row] = (float)k;
    }
    #pragma unroll
    for (int off = 32; off; off >>= 1) d += __shfl_down(d, off);
    if (l == 0) part[blockIdx.x * 4 + w] = d;
}

// ---- exact fp64 recheck + patch z/codes/diff for corrected rows ----
__global__ __launch_bounds__(256) void k_recheck(
        const float* __restrict__ x, const float* __restrict__ embT,
        const float* __restrict__ emb, const double* __restrict__ hn64,
        int* __restrict__ idx_out, const int* __restrict__ flag_cnt,
        const int* __restrict__ flagged, float* __restrict__ out,
        double* __restrict__ dcorr) {
    __shared__ double xd[DIM];
    __shared__ double wv[4];
    __shared__ int    wk[4];
    __shared__ int    old_sh, fk_sh;
    __shared__ double dsum[128];
    const int tid = threadIdx.x;
    const int cnt = flag_cnt[0];
    for (int f = blockIdx.x; f < cnt; f += gridDim.x) {
        const int row = flagged[f];
        __syncthreads();                       // reuse guard
        if (tid < DIM) xd[tid] = (double)x[(size_t)row * DIM + tid];
        if (tid == 0) old_sh = idx_out[row];
        __syncthreads();
        const float* tp = embT + tid;
        double s0 = 0.0, s1 = 0.0, s2 = 0.0, s3 = 0.0;
        #pragma unroll 4
        for (int j = 0; j < DIM; ++j) {
            const float* rp = tp + (size_t)j * KC;
            double xv = xd[j];
            s0 = fma((double)rp[0],   xv, s0);
            s1 = fma((double)rp[256], xv, s1);
            s2 = fma((double)rp[512], xv, s2);
            s3 = fma((double)rp[768], xv, s3);
        }
        double bv = s0 - hn64[tid];       int bk = tid;
        double v1 = s1 - hn64[tid + 256];
        if (v1 > bv) { bv = v1; bk = tid + 256; }
        double v2 = s2 - hn64[tid + 512];
        if (v2 > bv) { bv = v2; bk = tid + 512; }
        double v3 = s3 - hn64[tid + 768];
        if (v3 > bv) { bv = v3; bk = tid + 768; }
        #pragma unroll
        for (int m = 1; m < 64; m <<= 1) {
            double ov = __shfl_xor(bv, m);
            int    ok = __shfl_xor(bk, m);
            if (ov > bv || (ov == bv && ok < bk)) { bv = ov; bk = ok; }
        }
        const int w = tid >> 6;
        if ((tid & 63) == 0) { wv[w] = bv; wk[w] = bk; }
        __syncthreads();
        if (tid == 0) {
            double fv = wv[0]; int fk = wk[0];
            #pragma unroll
            for (int i = 1; i < 4; ++i)
                if (wv[i] > fv || (wv[i] == fv && wk[i] < fk)) { fv = wv[i]; fk = wk[i]; }
            fk_sh = fk;
        }
        __syncthreads();
        const int fk = fk_sh, old = old_sh;
        if (fk != old) {                      // patch z, codes, diff
            if (tid < DIM) {
                float xs = (float)xd[tid];
                float en = emb[(size_t)fk  * DIM + tid];
                float eo = emb[(size_t)old * DIM + tid];
                float dn = en - xs, dold = eo - xs;
                out[OUT_Z + (size_t)row * DIM + tid] = xs + dn;
                dsum[tid] = (double)dn * dn - (double)dold * dold;
            }
            __syncthreads();
            if (tid < 64) dsum[tid] += dsum[tid + 64];
            __syncthreads();
            if (tid < 64) {
                double v = dsum[tid];
                #pragma unroll
                for (int m = 32; m; m >>= 1) v += __shfl_down(v, m);
                if (tid == 0) {
                    atomicAdd(dcorr, v);
                    out[OUT_CODES + row] = (float)fk;
                    idx_out[row] = fk;
                }
            }
        }
    }
}

// ---- histogram (64 blocks) + finalize in last-done block ----
__global__ __launch_bounds__(256) void k_hist(
        const int* __restrict__ idx, unsigned* __restrict__ ghist,
        const float* __restrict__ part, const double* __restrict__ dcorr,
        unsigned* __restrict__ done, float* __restrict__ out) {
    __shared__ unsigned hist[KC];
    __shared__ double sh[256];
    __shared__ unsigned rank_sh;
    const int tid = threadIdx.x;
    #pragma unroll
    for (int i = 0; i < KC / 256; ++i) hist[i * 256 + tid] = 0u;
    __syncthreads();
    const int base = blockIdx.x * (NROWS / 64);
    #pragma unroll
    for (int it = 0; it < NROWS / 64 / 256; ++it)
        atomicAdd(&hist[idx[base + it * 256 + tid]], 1u);
    __syncthreads();
    #pragma unroll
    for (int i = 0; i < KC / 256; ++i) {
        unsigned c = hist[i * 256 + tid];
        if (c) atomicAdd(&ghist[i * 256 + tid], c);
    }
    __syncthreads();
    if (tid == 0) { __threadfence(); rank_sh = atomicAdd(done, 1u); }
    __syncthreads();
    if (rank_sh != 63) return;
    double s = 0.0;
    #pragma unroll
    for (int it = 0; it < 2048 / 256; ++it) s += (double)part[it * 256 + tid];
    sh[tid] = s;
    __syncthreads();
    for (int st = 128; st; st >>= 1) {
        if (tid < st) sh[tid] += sh[tid + st];
        __syncthreads();
    }
    double diff = (sh[0] + atomicAdd((double*)dcorr, 0.0)) * (1.0 / (double)XEL);
    double lp = 0.0;
    #pragma unroll
    for (int i = 0; i < KC / 256; ++i) {
        unsigned c = atomicAdd(&ghist[i * 256 + tid], 0u);   // coherent read
        double p = (double)c * (1.0 / (double)NROWS);
        lp += p * log(p + 1e-5);
    }
    __syncthreads();
    sh[tid] = lp;
    __syncthreads();
    for (int st = 128; st; st >>= 1) {
        if (tid < st) sh[tid] += sh[tid + st];
        __syncthreads();
    }
    if (tid == 0) {
        out[OUT_DIFF] = (float)diff;
        out[OUT_PPL]  = (float)(-sh[0]);
    }
}

extern "C" void kernel_launch(void* const* d_in, const int* in_sizes, int n_in,
                              void* d_out, int out_size, void* d_ws, size_t ws_size,
                              hipStream_t stream) {
    const float* x   = (const float*)d_in[0];
    const float* emb = (const float*)d_in[1];
    float* out = (float*)d_out;
    int*   wi  = (int*)d_ws;
    float* wf  = (float*)d_ws;
    unsigned* wu = (unsigned*)d_ws;
    double* hn64 = (double*)((float*)d_ws + WS_HN64);
    double* dcorr = (double*)((float*)d_ws + WS_DCOR);
    _Float16* ef = (_Float16*)((float*)d_ws + WS_EF);
    float* embT  = (float*)d_ws + WS_ET;

    k_prep<<<KC / 8, 256, 0, stream>>>(emb, ef, embT, wf + WS_HN, hn64, wu + WS_CNT);
    k_argmin<<<NROWS / 128, 256, 0, stream>>>(x, ef, emb, wf + WS_HN,
                                              wi + WS_IDX, wi + WS_CNT, wi + WS_FLAG,
                                              out, wf + WS_PART);
    k_recheck<<<1024, 256, 0, stream>>>(x, embT, emb, hn64, wi + WS_IDX,
                                        wi + WS_CNT, wi + WS_FLAG, out, dcorr);
    k_hist<<<64, 256, 0, stream>>>(wi + WS_IDX, wu + WS_HIST, wf + WS_PART,
                                   dcorr, wu + WS_DONE, out);
}

// Round 19
// 94.590 us; speedup vs baseline: 1.2339x; 1.0087x over previous
//
#include <hip/hip_runtime.h>
#include <math.h>

constexpr int DIM   = 128;
constexpr int KC    = 1024;
constexpr int NROWS = 65536;                 // 16384*512/128
constexpr int XEL   = NROWS * DIM;           // 8388608

// output layout (floats)
constexpr int OUT_Z     = 0;
constexpr int OUT_DIFF  = XEL;               // 8388608
constexpr int OUT_CODES = XEL + 1;           // 8388609
constexpr int OUT_PPL   = XEL + 1 + NROWS;   // 8454145

// ws layout (4-byte units)
constexpr int WS_IDX  = 0;                   // int[NROWS]
constexpr int WS_FLAG = NROWS;               // int[NROWS]
constexpr int WS_CNT  = 2 * NROWS;           // int   (zeroed by k_prep)
constexpr int WS_DONE = WS_CNT + 1;          // u32   (zeroed by k_prep)
constexpr int WS_DCOR = WS_CNT + 2;          // double (2 words, 8B-aligned, zeroed)
constexpr int WS_HIST = WS_DCOR + 2;         // u32[KC] (zeroed by k_prep)
constexpr int WS_HN   = WS_HIST + KC;        // float[KC]
constexpr int WS_PART = WS_HN + KC;          // float[4096] diff partials
constexpr int WS_HN64 = WS_PART + 4096;      // double[KC]
constexpr int WS_EF   = WS_HN64 + 2 * KC;    // _Float16[KC*DIM] = 65536 words
constexpr int WS_ET   = WS_EF + (KC * DIM / 2); // float[DIM*KC] = 131072 words

constexpr float GAP_THR = 0.06f;

typedef _Float16 f16x8 __attribute__((ext_vector_type(8)));
typedef _Float16 f16x4 __attribute__((ext_vector_type(4)));
typedef float f32x4 __attribute__((ext_vector_type(4)));

// ---- emb -> f16 + transposed fp32 + fp64 half-norms; zero counters/hist ----
__global__ __launch_bounds__(256) void k_prep(
        const float* __restrict__ emb, _Float16* __restrict__ ef,
        float* __restrict__ embT, float* __restrict__ hn,
        double* __restrict__ hn64, unsigned* __restrict__ zbase) {
    __shared__ float ldsT[DIM][9];
    const int tid = threadIdx.x;
    if (blockIdx.x == 0)
        for (int i = tid; i < 4 + KC; i += 256) zbase[i] = 0u;  // CNT,DONE,DCOR,HIST
    const int cc   = tid >> 5;
    const int code = blockIdx.x * 8 + cc;
    const int jq   = tid & 31;
    float4 v = *(const float4*)(emb + (size_t)code * DIM + jq * 4);
    f16x4 h = { (_Float16)v.x, (_Float16)v.y, (_Float16)v.z, (_Float16)v.w };
    *(f16x4*)(ef + (size_t)code * DIM + jq * 4) = h;
    ldsT[jq * 4 + 0][cc] = v.x;
    ldsT[jq * 4 + 1][cc] = v.y;
    ldsT[jq * 4 + 2][cc] = v.z;
    ldsT[jq * 4 + 3][cc] = v.w;
    double s = (double)v.x * v.x + (double)v.y * v.y
             + (double)v.z * v.z + (double)v.w * v.w;
    #pragma unroll
    for (int m = 1; m < 32; m <<= 1) s += __shfl_xor(s, m);
    if (jq == 0) {
        hn[code]   = (float)(0.5 * s);
        hn64[code] = 0.5 * s;
    }
    __syncthreads();
    #pragma unroll
    for (int i = 0; i < 4; ++i) {
        int idx = i * 256 + tid;
        int j = idx >> 3, c = idx & 7;
        embT[(size_t)j * KC + blockIdx.x * 8 + c] = ldsT[j][c];
    }
}

// ---- main: 4 waves x 16 rows (64 rows/block, grid 1024 -> 4 blocks/CU,
// 16 waves/CU = 4/SIMD). Double-buffered LDS via global_load_lds; acc
// initialized to -hn; fused z/codes/diff epilogue. ----
__global__ __launch_bounds__(256, 4) void k_argmin(
        const float* __restrict__ x, const _Float16* __restrict__ ef,
        const float* __restrict__ emb, const float* __restrict__ hn,
        int* __restrict__ idx_out, int* __restrict__ flag_cnt,
        int* __restrict__ flagged, float* __restrict__ out,
        float* __restrict__ part) {
    __shared__ _Float16 bt[2][8192];          // 2 x 16KB double buffer
    __shared__ float hn_lds[KC];              // 4KB
    __shared__ int idx_l[64];
    const int tid = threadIdx.x;
    const int l = tid & 63, w = tid >> 6;     // 4 waves
    const int lr = l & 15, lg = l >> 4;
    const int r0 = blockIdx.x * 64;           // 64 rows per block
    const int rw = r0 + w * 16;               // 16 rows per wave

    #pragma unroll
    for (int i = 0; i < 4; ++i) hn_lds[i * 256 + tid] = hn[i * 256 + tid];

    // A fragments: 16 rows as f16 (4 k-tiles), in registers
    f16x8 a[4];
    {
        const float* xr = x + (size_t)(rw + lr) * DIM + lg * 8;
        #pragma unroll
        for (int kt = 0; kt < 4; ++kt) {
            float4 v0 = *(const float4*)(xr + kt * 32);
            float4 v1 = *(const float4*)(xr + kt * 32 + 4);
            f16x8 av = { (_Float16)v0.x, (_Float16)v0.y, (_Float16)v0.z, (_Float16)v0.w,
                         (_Float16)v1.x, (_Float16)v1.y, (_Float16)v1.z, (_Float16)v1.w };
            a[kt] = av;
        }
    }

    // tile = 64 codes = 16 chunks; wave w stages code-group w's 4 kt-chunks.
    const _Float16* gsrc[4];
    #pragma unroll
    for (int i = 0; i < 4; ++i)
        gsrc[i] = ef + (size_t)(w * 16 + lr) * DIM + i * 32 + lg * 8;

    #define ISSUE_TILE(t, buf)                                                   \
        {                                                                        \
            _Pragma("unroll")                                                    \
            for (int i_ = 0; i_ < 4; ++i_) {                                     \
                const _Float16* g_ = gsrc[i_] + (size_t)(t) * 64 * DIM;          \
                __builtin_amdgcn_global_load_lds(                                \
                    (const __attribute__((address_space(1))) unsigned*)g_,       \
                    (__attribute__((address_space(3))) unsigned*)                \
                        &bt[buf][(w * 4 + i_) * 512],                            \
                    16, 0, 0);                                                   \
            }                                                                    \
        }

    ISSUE_TILE(0, 0)

    float m1[4], m2[4]; int bi[4];
    #pragma unroll
    for (int rg = 0; rg < 4; ++rg) { m1[rg] = -3e38f; m2[rg] = -3e38f; bi[rg] = 0; }

    constexpr int NT = KC / 64;               // 16 tiles
    for (int t = 0; t < NT; ++t) {
        const int buf = t & 1;
        if (t + 1 < NT) {
            ISSUE_TILE(t + 1, buf ^ 1)
            asm volatile("s_waitcnt vmcnt(4)" ::: "memory");  // own tile-t landed
        } else {
            asm volatile("s_waitcnt vmcnt(0)" ::: "memory");
        }
        __syncthreads();                      // all waves' tile-t stores visible
        f32x4 acc[4];
        #pragma unroll
        for (int c = 0; c < 4; ++c) {
            float nh = -hn_lds[t * 64 + c * 16 + lr];
            acc[c] = (f32x4){nh, nh, nh, nh};
        }
        __builtin_amdgcn_s_setprio(1);
        #pragma unroll
        for (int kt = 0; kt < 4; ++kt) {
            f16x8 b[4];
            #pragma unroll
            for (int c = 0; c < 4; ++c)
                b[c] = *(const f16x8*)(&bt[buf][(c * 4 + kt) * 512 + l * 8]);
            #pragma unroll
            for (int c = 0; c < 4; ++c)
                acc[c] = __builtin_amdgcn_mfma_f32_16x16x32_f16(a[kt], b[c], acc[c], 0, 0, 0);
        }
        __builtin_amdgcn_s_setprio(0);
        #pragma unroll
        for (int c = 0; c < 4; ++c) {
            const int cc = t * 64 + c * 16 + lr;
            #pragma unroll
            for (int rg = 0; rg < 4; ++rg) {
                float v = acc[c][rg];
                bool g = v > m1[rg];
                // m1>=m2 invariant -> max(min(v,m1),m2) == new second-best
                m2[rg] = fmaxf(fminf(v, m1[rg]), m2[rg]);
                m1[rg] = fmaxf(m1[rg], v);
                bi[rg] = g ? cc : bi[rg];
            }
        }
        __syncthreads();                      // all waves done reading bt[buf]
    }
    #undef ISSUE_TILE

    // merge top-2 across the 16 lanes sharing each row
    #pragma unroll
    for (int rg = 0; rg < 4; ++rg) {
        float a1 = m1[rg], a2 = m2[rg]; int ai = bi[rg];
        #pragma unroll
        for (int mask = 1; mask < 16; mask <<= 1) {
            float o1 = __shfl_xor(a1, mask);
            float o2 = __shfl_xor(a2, mask);
            int   oi = __shfl_xor(ai, mask);
            float nm2 = fmaxf(fmaxf(a2, o2), fminf(a1, o1));
            if (o1 > a1 || (o1 == a1 && oi < ai)) { a1 = o1; ai = oi; }
            a2 = nm2;
        }
        if (lr == 0) {
            int rl = w * 16 + lg * 4 + rg;
            int row = r0 + rl;
            idx_out[row] = ai;
            idx_l[rl] = ai;
            if (a1 - a2 < GAP_THR) {          // near-tie: exact recheck later
                int p = atomicAdd(flag_cnt, 1);
                flagged[p] = row;
            }
        }
    }
    __syncthreads();                          // idx_l visible to all

    // ---- fused epilogue: z, codes, diff partials (half-wave per row) ----
    const int c = tid & 31;                   // float4 column 0..31
    float d = 0.f;
    #pragma unroll
    for (int it = 0; it < 8; ++it) {
        const int rl = it * 8 + (tid >> 5);   // 8 rows per iteration
        const int row = r0 + rl;
        const int k = idx_l[rl];
        float4 xv = *(const float4*)(x + (size_t)row * DIM + c * 4);
        float4 qv = *(const float4*)(emb + (size_t)k * DIM + c * 4);
        float dx = qv.x - xv.x, dy = qv.y - xv.y, dz = qv.z - xv.z, dw = qv.w - xv.w;
        float4 z;
        z.x = xv.x + dx; z.y = xv.y + dy; z.z = xv.z + dz; z.w = xv.w + dw;
        *(float4*)(out + OUT_Z + (size_t)row * DIM + c * 4) = z;
        d += dx*dx + dy*dy + dz*dz + dw*dw;
        if (c == 0) out[OUT_CODES + row] = (float)k;
    }
    #pragma unroll
    for (int off = 32; off; off >>= 1) d += __shfl_down(d, off);
    if (l == 0) part[blockIdx.x * 4 + w] = d;
}

// ---- exact fp64 recheck + patch z/codes/diff for corrected rows ----
__global__ __launch_bounds__(256) void k_recheck(
        const float* __restrict__ x, const float* __restrict__ embT,
        const float* __restrict__ emb, const double* __restrict__ hn64,
        int* __restrict__ idx_out, const int* __restrict__ flag_cnt,
        const int* __restrict__ flagged, float* __restrict__ out,
        double* __restrict__ dcorr) {
    __shared__ double xd[DIM];
    __shared__ double wv[4];
    __shared__ int    wk[4];
    __shared__ int    old_sh, fk_sh;
    __shared__ double dsum[128];
    const int tid = threadIdx.x;
    const int cnt = flag_cnt[0];
    for (int f = blockIdx.x; f < cnt; f += gridDim.x) {
        const int row = flagged[f];
        __syncthreads();                       // reuse guard
        if (tid < DIM) xd[tid] = (double)x[(size_t)row * DIM + tid];
        if (tid == 0) old_sh = idx_out[row];
        __syncthreads();
        const float* tp = embT + tid;
        double s0 = 0.0, s1 = 0.0, s2 = 0.0, s3 = 0.0;
        #pragma unroll 4
        for (int j = 0; j < DIM; ++j) {
            const float* rp = tp + (size_t)j * KC;
            double xv = xd[j];
            s0 = fma((double)rp[0],   xv, s0);
            s1 = fma((double)rp[256], xv, s1);
            s2 = fma((double)rp[512], xv, s2);
            s3 = fma((double)rp[768], xv, s3);
        }
        double bv = s0 - hn64[tid];       int bk = tid;
        double v1 = s1 - hn64[tid + 256];
        if (v1 > bv) { bv = v1; bk = tid + 256; }
        double v2 = s2 - hn64[tid + 512];
        if (v2 > bv) { bv = v2; bk = tid + 512; }
        double v3 = s3 - hn64[tid + 768];
        if (v3 > bv) { bv = v3; bk = tid + 768; }
        #pragma unroll
        for (int m = 1; m < 64; m <<= 1) {
            double ov = __shfl_xor(bv, m);
            int    ok = __shfl_xor(bk, m);
            if (ov > bv || (ov == bv && ok < bk)) { bv = ov; bk = ok; }
        }
        const int w = tid >> 6;
        if ((tid & 63) == 0) { wv[w] = bv; wk[w] = bk; }
        __syncthreads();
        if (tid == 0) {
            double fv = wv[0]; int fk = wk[0];
            #pragma unroll
            for (int i = 1; i < 4; ++i)
                if (wv[i] > fv || (wv[i] == fv && wk[i] < fk)) { fv = wv[i]; fk = wk[i]; }
            fk_sh = fk;
        }
        __syncthreads();
        const int fk = fk_sh, old = old_sh;
        if (fk != old) {                      // patch z, codes, diff
            if (tid < DIM) {
                float xs = (float)xd[tid];
                float en = emb[(size_t)fk  * DIM + tid];
                float eo = emb[(size_t)old * DIM + tid];
                float dn = en - xs, dold = eo - xs;
                out[OUT_Z + (size_t)row * DIM + tid] = xs + dn;
                dsum[tid] = (double)dn * dn - (double)dold * dold;
            }
            __syncthreads();
            if (tid < 64) dsum[tid] += dsum[tid + 64];
            __syncthreads();
            if (tid < 64) {
                double v = dsum[tid];
                #pragma unroll
                for (int m = 32; m; m >>= 1) v += __shfl_down(v, m);
                if (tid == 0) {
                    atomicAdd(dcorr, v);
                    out[OUT_CODES + row] = (float)fk;
                    idx_out[row] = fk;
                }
            }
        }
    }
}

// ---- histogram (64 blocks) + finalize in last-done block ----
__global__ __launch_bounds__(256) void k_hist(
        const int* __restrict__ idx, unsigned* __restrict__ ghist,
        const float* __restrict__ part, const double* __restrict__ dcorr,
        unsigned* __restrict__ done, float* __restrict__ out) {
    __shared__ unsigned hist[KC];
    __shared__ double sh[256];
    __shared__ unsigned rank_sh;
    const int tid = threadIdx.x;
    #pragma unroll
    for (int i = 0; i < KC / 256; ++i) hist[i * 256 + tid] = 0u;
    __syncthreads();
    const int base = blockIdx.x * (NROWS / 64);
    #pragma unroll
    for (int it = 0; it < NROWS / 64 / 256; ++it)
        atomicAdd(&hist[idx[base + it * 256 + tid]], 1u);
    __syncthreads();
    #pragma unroll
    for (int i = 0; i < KC / 256; ++i) {
        unsigned c = hist[i * 256 + tid];
        if (c) atomicAdd(&ghist[i * 256 + tid], c);
    }
    __syncthreads();
    if (tid == 0) { __threadfence(); rank_sh = atomicAdd(done, 1u); }
    __syncthreads();
    if (rank_sh != 63) return;
    double s = 0.0;
    #pragma unroll
    for (int it = 0; it < 4096 / 256; ++it) s += (double)part[it * 256 + tid];
    sh[tid] = s;
    __syncthreads();
    for (int st = 128; st; st >>= 1) {
        if (tid < st) sh[tid] += sh[tid + st];
        __syncthreads();
    }
    double diff = (sh[0] + atomicAdd((double*)dcorr, 0.0)) * (1.0 / (double)XEL);
    double lp = 0.0;
    #pragma unroll
    for (int i = 0; i < KC / 256; ++i) {
        unsigned c = atomicAdd(&ghist[i * 256 + tid], 0u);   // coherent read
        double p = (double)c * (1.0 / (double)NROWS);
        lp += p * log(p + 1e-5);
    }
    __syncthreads();
    sh[tid] = lp;
    __syncthreads();
    for (int st = 128; st; st >>= 1) {
        if (tid < st) sh[tid] += sh[tid + st];
        __syncthreads();
    }
    if (tid == 0) {
        out[OUT_DIFF] = (float)diff;
        out[OUT_PPL]  = (float)(-sh[0]);
    }
}

extern "C" void kernel_launch(void* const* d_in, const int* in_sizes, int n_in,
                              void* d_out, int out_size, void* d_ws, size_t ws_size,
                              hipStream_t stream) {
    const float* x   = (const float*)d_in[0];
    const float* emb = (const float*)d_in[1];
    float* out = (float*)d_out;
    int*   wi  = (int*)d_ws;
    float* wf  = (float*)d_ws;
    unsigned* wu = (unsigned*)d_ws;
    double* hn64 = (double*)((float*)d_ws + WS_HN64);
    double* dcorr = (double*)((float*)d_ws + WS_DCOR);
    _Float16* ef = (_Float16*)((float*)d_ws + WS_EF);
    float* embT  = (float*)d_ws + WS_ET;

    k_prep<<<KC / 8, 256, 0, stream>>>(emb, ef, embT, wf + WS_HN, hn64, wu + WS_CNT);
    k_argmin<<<NROWS / 64, 256, 0, stream>>>(x, ef, emb, wf + WS_HN,
                                             wi + WS_IDX, wi + WS_CNT, wi + WS_FLAG,
                                             out, wf + WS_PART);
    k_recheck<<<1024, 256, 0, stream>>>(x, embT, emb, hn64, wi + WS_IDX,
                                        wi + WS_CNT, wi + WS_FLAG, out, dcorr);
    k_hist<<<64, 256, 0, stream>>>(wi + WS_IDX, wu + WS_HIST, wf + WS_PART,
                                   dcorr, wu + WS_DONE, out);
}